// Round 2
// baseline (546.130 us; speedup 1.0000x reference)
//
#include <hip/hip_runtime.h>
#include <hip/hip_bf16.h>
#include <stdint.h>

// ---------------------------------------------------------------------------
// BlockSparse: out = x @ (mask*W)^T + bias
//   Mask pattern known: 256x256 block (bi,bj) kept iff ((bi+bj)%16) >= 8.
// R2: single fused f32->bf16 cvt kernel; GEMM gains XOR bank-swizzle on the
//     LDS k-granules, grouped block ordering for L2 reuse, launch_bounds(256,4).
// ---------------------------------------------------------------------------

typedef __bf16 bf16x8 __attribute__((ext_vector_type(8)));
typedef float  f32x4  __attribute__((ext_vector_type(4)));

#define AS1 __attribute__((address_space(1)))
#define AS3 __attribute__((address_space(3)))

__device__ __forceinline__ void async_cp16(const void* g, void* l) {
  // 16B/lane direct global->LDS; LDS dest is wave-uniform base + lane*16 (linear).
  __builtin_amdgcn_global_load_lds((const AS1 void*)g, (AS3 void*)l, 16, 0, 0);
}

// --------------------------- f32 -> bf16 (RNE) ------------------------------
__device__ __forceinline__ uint32_t pack_bf16(float a, float b) {
  uint32_t ua = __float_as_uint(a);
  ua += 0x7fffu + ((ua >> 16) & 1u);
  uint32_t ub = __float_as_uint(b);
  ub += 0x7fffu + ((ub >> 16) & 1u);
  return (ua >> 16) | (ub & 0xffff0000u);
}

// One kernel converts BOTH x and w. chunk = 8 floats in, 16 B out.
__global__ __launch_bounds__(256) void cvt_both(const float* __restrict__ x,
                                                const float* __restrict__ w,
                                                uint32_t* __restrict__ xb,
                                                uint32_t* __restrict__ wb,
                                                int nx8, int ntot8) {
  int stride = gridDim.x * 256;
  for (int i = blockIdx.x * 256 + threadIdx.x; i < ntot8; i += stride) {
    const float* src;
    uint32_t* dst;
    int j;
    if (i < nx8) { src = x; dst = xb; j = i; }
    else         { src = w; dst = wb; j = i - nx8; }
    const float4* p = (const float4*)src + (size_t)j * 2;
    float4 a = p[0];
    float4 b = p[1];
    uint4 r;
    r.x = pack_bf16(a.x, a.y);
    r.y = pack_bf16(a.z, a.w);
    r.z = pack_bf16(b.x, b.y);
    r.w = pack_bf16(b.z, b.w);
    ((uint4*)dst)[j] = r;
  }
}

// ------------------------------- GEMM ---------------------------------------
// C[m,n] = sum_k X[m,k]*W[n,k] + bias[n], only kept 256-wide k-blocks.
// 256 thr = 4 waves; C-tile 128x128; wave -> 64x64 = 4x4 MFMA 16x16x32.
// LDS tile: 128 rows x 32 k (64 B/row), k-granules (16B) XOR-swizzled by row&3.
__global__ __launch_bounds__(256, 4) void gemm_bs(
    const uint16_t* __restrict__ X,   // [8192][4096] bf16 bits
    const uint16_t* __restrict__ W,   // [4096][4096] bf16 bits
    const float* __restrict__ bias,   // [4096]
    float* __restrict__ out) {        // [8192][4096] f32
  constexpr int K = 4096;
  __shared__ uint16_t sA[128 * 32];
  __shared__ uint16_t sB[128 * 32];

  const int tid = threadIdx.x;

  // grouped pid: 8 m-tiles per group, n sweeps within group -> L2 reuse
  const int pid = blockIdx.x;              // 0..2047
  constexpr int NPN = 32;                  // n tiles
  constexpr int GRP = 8;                   // m tiles per group
  const int gid = pid / (GRP * NPN);
  const int rem = pid % (GRP * NPN);
  const int bm = gid * GRP + (rem % GRP);  // 0..63
  const int bn = rem / GRP;                // 0..31
  const int m0 = bm << 7;
  const int n0 = bn << 7;
  const int bi = bn >> 1;                  // weight 256-block row

  // staging: thread t -> LDS linear offset t*16; source k-granule XOR-swizzled
  const int tr = tid >> 2;                                   // row-in-shot 0..63
  const int tc = (((tid & 3) ^ (tr & 3)) << 3);              // swizzled k elem
  const uint16_t* gA0 = X + (size_t)(m0 + tr) * K + tc;
  const uint16_t* gA1 = X + (size_t)(m0 + 64 + tr) * K + tc;
  const uint16_t* gB0 = W + (size_t)(n0 + tr) * K + tc;
  const uint16_t* gB1 = W + (size_t)(n0 + 64 + tr) * K + tc;
  uint16_t* lA0 = sA + tid * 8;
  uint16_t* lA1 = sA + 2048 + tid * 8;
  uint16_t* lB0 = sB + tid * 8;
  uint16_t* lB1 = sB + 2048 + tid * 8;

  // fragment coords
  const int lane = tid & 63;
  const int wv = tid >> 6;
  const int wm = (wv >> 1) << 6;
  const int wn = (wv & 1) << 6;
  const int fr = lane & 15;
  // logical k-granule lane>>4, physical = ^(row&3); row&3 == fr&3 always
  const int fkp = (((lane >> 4) ^ (fr & 3)) << 3);

  f32x4 acc[4][4];
#pragma unroll
  for (int i = 0; i < 4; ++i)
#pragma unroll
    for (int j = 0; j < 4; ++j)
      acc[i][j] = (f32x4){0.f, 0.f, 0.f, 0.f};

  for (int t = 0; t < 8; ++t) {
    const int kb = ((24 + t - bi) & 15) << 8;   // kept 256-block base
#pragma unroll
    for (int u = 0; u < 8; ++u) {
      const int kg = kb + (u << 5);
      __syncthreads();
      async_cp16(gA0 + kg, lA0);
      async_cp16(gA1 + kg, lA1);
      async_cp16(gB0 + kg, lB0);
      async_cp16(gB1 + kg, lB1);
      __syncthreads();

      bf16x8 av[4], bv[4];
#pragma unroll
      for (int i = 0; i < 4; ++i)
        av[i] = *(const bf16x8*)(sA + ((wm + (i << 4) + fr) << 5) + fkp);
#pragma unroll
      for (int j = 0; j < 4; ++j)
        bv[j] = *(const bf16x8*)(sB + ((wn + (j << 4) + fr) << 5) + fkp);
#pragma unroll
      for (int i = 0; i < 4; ++i)
#pragma unroll
        for (int j = 0; j < 4; ++j)
          acc[i][j] = __builtin_amdgcn_mfma_f32_16x16x32_bf16(av[i], bv[j],
                                                              acc[i][j], 0, 0, 0);
    }
  }

  // epilogue: D lane map col=lane&15, row=(lane>>4)*4+r
  const int rq = (lane >> 4) << 2;
#pragma unroll
  for (int j = 0; j < 4; ++j) {
    const int c = n0 + wn + (j << 4) + fr;
    const float bz = bias[c];
#pragma unroll
    for (int i = 0; i < 4; ++i) {
      const int r0 = m0 + wm + (i << 4) + rq;
#pragma unroll
      for (int r = 0; r < 4; ++r)
        out[(size_t)(r0 + r) * 4096 + c] = acc[i][j][r] + bz;
    }
  }
}

// ----------------------------------------------------------------------------
extern "C" void kernel_launch(void* const* d_in, const int* in_sizes, int n_in,
                              void* d_out, int out_size, void* d_ws, size_t ws_size,
                              hipStream_t stream) {
  const float* x = (const float*)d_in[0];
  const float* w = (const float*)d_in[1];
  const float* bias = (const float*)d_in[2];
  float* out = (float*)d_out;

  uint16_t* xb = (uint16_t*)d_ws;                  // 64 MiB
  uint16_t* wb = xb + (size_t)8192 * 4096;         // 32 MiB

  const int nx8 = (8192 * 4096) / 8;
  const int nw8 = (4096 * 4096) / 8;
  const int ntot8 = nx8 + nw8;
  // 2048 blocks * 256 thr, grid-stride: each thread ~12 chunks
  hipLaunchKernelGGL(cvt_both, dim3(2048), dim3(256), 0, stream,
                     x, w, (uint32_t*)xb, (uint32_t*)wb, nx8, ntot8);

  hipLaunchKernelGGL(gemm_bs, dim3(2048), dim3(256), 0, stream,
                     (const uint16_t*)xb, (const uint16_t*)wb, bias, out);
}

// Round 3
// 515.803 us; speedup vs baseline: 1.0588x; 1.0588x over previous
//
#include <hip/hip_runtime.h>
#include <hip/hip_bf16.h>
#include <stdint.h>

// ---------------------------------------------------------------------------
// BlockSparse: out = x @ (mask*W)^T + bias
//   Mask pattern known: 256x256 block (bi,bj) kept iff ((bi+bj)%16) >= 8.
// R3: revert to R1 row-major block order (R2 grouping cost +220MB FETCH);
//     BK 32->64 to halve barrier-drain count (32 stages of 32KB, LDS 32KB,
//     occupancy preserved at 4 blocks/CU); 8-granule XOR swizzle keeps the
//     128B-row ds_read_b128 conflict-free while LDS dest stays linear.
// Note: SQ_LDS_BANK_CONFLICT == 524288*32 is structural to global_load_lds
//     16B writes, NOT ds_reads (R2 evidence: identical count under swizzle).
// ---------------------------------------------------------------------------

typedef __bf16 bf16x8 __attribute__((ext_vector_type(8)));
typedef float  f32x4  __attribute__((ext_vector_type(4)));

#define AS1 __attribute__((address_space(1)))
#define AS3 __attribute__((address_space(3)))

__device__ __forceinline__ void async_cp16(const void* g, void* l) {
  // 16B/lane direct global->LDS; dest = wave-uniform base + lane*16 (linear).
  __builtin_amdgcn_global_load_lds((const AS1 void*)g, (AS3 void*)l, 16, 0, 0);
}

// --------------------------- f32 -> bf16 (RNE) ------------------------------
__device__ __forceinline__ uint32_t pack_bf16(float a, float b) {
  uint32_t ua = __float_as_uint(a);
  ua += 0x7fffu + ((ua >> 16) & 1u);
  uint32_t ub = __float_as_uint(b);
  ub += 0x7fffu + ((ub >> 16) & 1u);
  return (ua >> 16) | (ub & 0xffff0000u);
}

__global__ __launch_bounds__(256) void cvt_both(const float* __restrict__ x,
                                                const float* __restrict__ w,
                                                uint32_t* __restrict__ xb,
                                                uint32_t* __restrict__ wb,
                                                int nx8, int ntot8) {
  int stride = gridDim.x * 256;
  for (int i = blockIdx.x * 256 + threadIdx.x; i < ntot8; i += stride) {
    const float* src;
    uint32_t* dst;
    int j;
    if (i < nx8) { src = x; dst = xb; j = i; }
    else         { src = w; dst = wb; j = i - nx8; }
    const float4* p = (const float4*)src + (size_t)j * 2;
    float4 a = p[0];
    float4 b = p[1];
    uint4 r;
    r.x = pack_bf16(a.x, a.y);
    r.y = pack_bf16(a.z, a.w);
    r.z = pack_bf16(b.x, b.y);
    r.w = pack_bf16(b.z, b.w);
    ((uint4*)dst)[j] = r;
  }
}

// ------------------------------- GEMM ---------------------------------------
// C[m,n] = sum_k X[m,k]*W[n,k] + bias[n], only kept 256-wide k-blocks.
// 256 thr = 4 waves; C-tile 128x128; wave -> 64x64 = 4x4 MFMA 16x16x32.
// LDS tile: 128 rows x 64 k (128 B/row); 16B granule g at row r holds logical
// granule g^(r&7)  (source-swizzled so global_load_lds dest stays linear).
__global__ __launch_bounds__(256, 4) void gemm_bs(
    const uint16_t* __restrict__ X,   // [8192][4096] bf16 bits
    const uint16_t* __restrict__ W,   // [4096][4096] bf16 bits
    const float* __restrict__ bias,   // [4096]
    float* __restrict__ out) {        // [8192][4096] f32
  constexpr int K = 4096;
  __shared__ uint16_t sA[128 * 64];   // 16 KB
  __shared__ uint16_t sB[128 * 64];   // 16 KB

  const int tid = threadIdx.x;
  const int bn = blockIdx.x;          // 0..31 (fast -> good XCD/L2 behavior)
  const int bm = blockIdx.y;          // 0..63
  const int m0 = bm << 7;
  const int n0 = bn << 7;
  const int bi = bn >> 1;             // weight 256-block row

  // staging: shot s covers rows s*32 + (tid>>3); thread stages 16B into
  // physical granule tid&7 of its row; source granule XOR-swizzled by row&7.
  const int sr = tid >> 3;                          // row-in-shot 0..31
  const int tc = (((tid & 7) ^ (sr & 7)) << 3);     // swizzled src k-elem
  const uint16_t* gA[4];
  const uint16_t* gB[4];
  uint16_t* lA[4];
  uint16_t* lB[4];
#pragma unroll
  for (int s = 0; s < 4; ++s) {
    gA[s] = X + (size_t)(m0 + (s << 5) + sr) * K + tc;
    gB[s] = W + (size_t)(n0 + (s << 5) + sr) * K + tc;
    lA[s] = sA + (s << 11) + tid * 8;
    lB[s] = sB + (s << 11) + tid * 8;
  }

  // fragment coords
  const int lane = tid & 63;
  const int wv = tid >> 6;
  const int wm = (wv >> 1) << 6;
  const int wn = (wv & 1) << 6;
  const int fr = lane & 15;
  const int g0 = lane >> 4;           // logical k-granule within MFMA k-step

  f32x4 acc[4][4];
#pragma unroll
  for (int i = 0; i < 4; ++i)
#pragma unroll
    for (int j = 0; j < 4; ++j)
      acc[i][j] = (f32x4){0.f, 0.f, 0.f, 0.f};

  for (int t = 0; t < 8; ++t) {
    const int kb = ((24 + t - bi) & 15) << 8;   // kept 256-block base
#pragma unroll
    for (int u = 0; u < 4; ++u) {
      const int kg = kb + (u << 6);
      __syncthreads();                 // prior reads done before overwrite
#pragma unroll
      for (int s = 0; s < 4; ++s) async_cp16(gA[s] + kg, lA[s]);
#pragma unroll
      for (int s = 0; s < 4; ++s) async_cp16(gB[s] + kg, lB[s]);
      __syncthreads();                 // drains vmcnt(0): staging visible

#pragma unroll
      for (int kk = 0; kk < 2; ++kk) {
        bf16x8 av[4], bv[4];
#pragma unroll
        for (int i = 0; i < 4; ++i) {
          const int row = wm + (i << 4) + fr;
          const int pg = ((kk << 2) + g0) ^ (fr & 7);
          av[i] = *(const bf16x8*)(sA + (row << 6) + (pg << 3));
        }
#pragma unroll
        for (int j = 0; j < 4; ++j) {
          const int row = wn + (j << 4) + fr;
          const int pg = ((kk << 2) + g0) ^ (fr & 7);
          bv[j] = *(const bf16x8*)(sB + (row << 6) + (pg << 3));
        }
#pragma unroll
        for (int i = 0; i < 4; ++i)
#pragma unroll
          for (int j = 0; j < 4; ++j)
            acc[i][j] = __builtin_amdgcn_mfma_f32_16x16x32_bf16(av[i], bv[j],
                                                                acc[i][j], 0, 0, 0);
      }
    }
  }

  // epilogue: D lane map col=lane&15, row=(lane>>4)*4+r  [m89-verified]
  const int rq = (lane >> 4) << 2;
#pragma unroll
  for (int j = 0; j < 4; ++j) {
    const int c = n0 + wn + (j << 4) + fr;
    const float bz = bias[c];
#pragma unroll
    for (int i = 0; i < 4; ++i) {
      const int r0 = m0 + wm + (i << 4) + rq;
#pragma unroll
      for (int r = 0; r < 4; ++r)
        out[(size_t)(r0 + r) * 4096 + c] = acc[i][j][r] + bz;
    }
  }
}

// ----------------------------------------------------------------------------
extern "C" void kernel_launch(void* const* d_in, const int* in_sizes, int n_in,
                              void* d_out, int out_size, void* d_ws, size_t ws_size,
                              hipStream_t stream) {
  const float* x = (const float*)d_in[0];
  const float* w = (const float*)d_in[1];
  const float* bias = (const float*)d_in[2];
  float* out = (float*)d_out;

  uint16_t* xb = (uint16_t*)d_ws;                  // 64 MiB
  uint16_t* wb = xb + (size_t)8192 * 4096;         // 32 MiB

  const int nx8 = (8192 * 4096) / 8;
  const int nw8 = (4096 * 4096) / 8;
  const int ntot8 = nx8 + nw8;
  hipLaunchKernelGGL(cvt_both, dim3(2048), dim3(256), 0, stream,
                     x, w, (uint32_t*)xb, (uint32_t*)wb, nx8, ntot8);

  hipLaunchKernelGGL(gemm_bs, dim3(32, 64), dim3(256), 0, stream,
                     (const uint16_t*)xb, (const uint16_t*)wb, bias, out);
}